// Round 4
// baseline (115.473 us; speedup 1.0000x reference)
//
#include <hip/hip_runtime.h>

// SKA 2D: out[b, g*8+cw, h, w] = sum_{i,j} x[b, g*8+cw, h+i-1, w+j-1] * w[b, cw, 3i+j, h, w]
// B=8, C=64, H=W=128, C_w=8, ks=3, groups=8. fp32. Memory-bound, ideal ~105 MB HBM.
//
// Block = (b, cw, 16-row tile), 512 threads. Stage x for all 8 groups
// (8 ch x 18 rows x 128 cols = 72 KB LDS, 1.125x redundancy) with coalesced
// float4 loads; weights in 9 float4 regs/thread (nontemporal — zero reuse);
// horizontal halos via wave shuffles; out stores nontemporal. blockIdx
// swizzled so each XCD owns one batch (halo reuse in its L2).

#define SKA_W 128
#define SKA_HW (128 * 128)
#define TILE_ROWS 16
#define STAGE_ROWS 18

typedef float vf4 __attribute__((ext_vector_type(4)));  // clang-native for nontemporal builtins

__global__ __launch_bounds__(512, 4) void SKA_44830868635847_kernel(
        const float* __restrict__ x,
        const float* __restrict__ wgt,
        float* __restrict__ out) {
    __shared__ float lds[8 * STAGE_ROWS * SKA_W];  // 73728 B -> 2 blocks/CU

    // XCD-aware swizzle: hardware round-robins blockIdx % 8 across XCDs.
    // Give XCD k the contiguous bid range [64k, 64k+64) == batch k.
    const int raw = blockIdx.x;
    const int bid = (raw & 7) * 64 + (raw >> 3);
    const int htile = bid & 7;           // 8 row-tiles of 16
    const int cw    = (bid >> 3) & 7;
    const int b     = bid >> 6;
    const int h0    = htile * TILE_ROWS;

    const int t  = threadIdx.x;
    const int w4 = t & 31;               // 32 float4-chunks across W
    const int hl = t >> 5;               // 16 rows per block
    const int h  = h0 + hl;
    const int w0 = w4 * 4;

    // ---- weights: 9 float4/thread, loaded once, reused across all 8 groups.
    // Streamed (no reuse anywhere) -> nontemporal.
    const float* wbase = wgt + ((size_t)(b * 8 + cw) * 9) * SKA_HW + h * SKA_W + w0;
    vf4 wv[9];
#pragma unroll
    for (int k = 0; k < 9; ++k)
        wv[k] = __builtin_nontemporal_load((const vf4*)(wbase + (size_t)k * SKA_HW));

    // ---- stage x: 8 channels x 18 rows x 128 cols, coalesced float4.
    // 4608 chunks / 512 threads = 9 per thread.
    const float* xb = x + (size_t)(b * 64 + cw) * SKA_HW;
#pragma unroll
    for (int rep = 0; rep < 9; ++rep) {
        int idx = rep * 512 + t;
        int ch  = idx / 576;             // 576 chunks per channel (18 rows x 32)
        int rem = idx - ch * 576;
        int r   = rem >> 5;
        int c4  = rem & 31;
        int xrow = h0 - 1 + r;
        vf4 v = (vf4)(0.f);
        if ((unsigned)xrow < 128u)       // zero-pad rows outside the image
            v = *(const vf4*)(xb + (size_t)ch * 8 * SKA_HW + xrow * SKA_W + c4 * 4);
        *(vf4*)&lds[(ch * STAGE_ROWS + r) * SKA_W + c4 * 4] = v;
    }
    __syncthreads();

    // ---- compute: per group, 3 row taps from LDS; horizontal halos via shuffle
    const size_t obase = (size_t)(b * 64 + cw) * SKA_HW + (size_t)h * SKA_W + w0;
#pragma unroll
    for (int g = 0; g < 8; ++g) {
        vf4 acc = (vf4)(0.f);
#pragma unroll
        for (int i = 0; i < 3; ++i) {
            const float* lrow = &lds[(g * STAGE_ROWS + hl + i) * SKA_W + w0];
            vf4 mid = *(const vf4*)lrow;
            // halos from lane-adjacent chunk (w4 +- 1); lane 0/32 have w4==0,
            // lane 31/63 have w4==31, so cross-row shuffles are always masked.
            float xl  = __shfl_up(mid.w, 1);
            xl  = (w4 == 0)  ? 0.f : xl;
            float xr4 = __shfl_down(mid.x, 1);
            xr4 = (w4 == 31) ? 0.f : xr4;
            vf4 wl = wv[i * 3 + 0];
            vf4 wm = wv[i * 3 + 1];
            vf4 wr = wv[i * 3 + 2];
            acc.x += wl.x * xl    + wm.x * mid.x + wr.x * mid.y;
            acc.y += wl.y * mid.x + wm.y * mid.y + wr.y * mid.z;
            acc.z += wl.z * mid.y + wm.z * mid.z + wr.z * mid.w;
            acc.w += wl.w * mid.z + wm.w * mid.w + wr.w * xr4;
        }
        __builtin_nontemporal_store(acc, (vf4*)(out + obase + (size_t)g * 8 * SKA_HW));
    }
}

extern "C" void kernel_launch(void* const* d_in, const int* in_sizes, int n_in,
                              void* d_out, int out_size, void* d_ws, size_t ws_size,
                              hipStream_t stream) {
    const float* x   = (const float*)d_in[0];  // (8, 64, 128, 128)
    const float* wgt = (const float*)d_in[1];  // (8, 8, 9, 128, 128)
    float* out = (float*)d_out;                // (8, 64, 128, 128)

    // blocks = B * C_w * (H / TILE_ROWS) = 8*8*8 = 512, 512 threads each
    SKA_44830868635847_kernel<<<512, 512, 0, stream>>>(x, wgt, out);
}

// Round 5
// 102.663 us; speedup vs baseline: 1.1248x; 1.1248x over previous
//
#include <hip/hip_runtime.h>
#include <stdint.h>

// SKA 2D: out[b, g*8+cw, h, w] = sum_{i,j} x[b, g*8+cw, h+i-1, w+j-1] * w[b, cw, 3i+j, h, w]
// B=8, C=64, H=W=128, C_w=8, ks=3, groups=8. fp32. Memory-bound, ideal ~105 MB HBM.
//
// R2-proven base: block = (b, cw, 8-row tile), 256 threads, 40 KB LDS
// (8 ch x 10 rows x 128 cols), 4 blocks/CU. This round: stage x via async
// global_load_lds dwordx4 (LDS layout is exactly linear: byte off = idx*16 =
// wave-uniform base + lane*16). Out-of-image rows are staged CLAMPED and the
// corresponding boundary-tap weights zeroed (garbage * 0 == 0), so the DMA
// path needs no predication. Weights: 9 float4 regs/thread, reused across all
// 8 groups (exact 1x w traffic). Horizontal halos via wave shuffles.

#define SKA_W 128
#define SKA_HW (128 * 128)
#define TILE_ROWS 8
#define STAGE_ROWS 10

typedef float vf4 __attribute__((ext_vector_type(4)));

__global__ __launch_bounds__(256, 4) void SKA_44830868635847_kernel(
        const float* __restrict__ x,
        const float* __restrict__ wgt,
        float* __restrict__ out) {
    __shared__ float lds[8 * STAGE_ROWS * SKA_W];  // 40 KiB -> 4 blocks/CU

    const int t     = threadIdx.x;
    const int bid   = blockIdx.x;
    const int htile = bid & 15;          // 16 row-tiles of 8
    const int cw    = (bid >> 4) & 7;
    const int b     = bid >> 7;
    const int h0    = htile * TILE_ROWS;

    const int w4 = t & 31;               // 32 float4-chunks across W
    const int hl = t >> 5;               // 8 rows per block
    const int h  = h0 + hl;
    const int w0 = w4 * 4;

    // ---- async stage x: 8 channels x 10 rows x 128 cols, global_load_lds x16.
    // 2560 chunks / 256 threads = 10 per thread. LDS dest is wave-uniform
    // base + lane*16 (layout is linear in chunk index). Rows clamped at the
    // image edge; boundary taps neutralized via zeroed weights below.
    const float* xb = x + (size_t)(b * 64 + cw) * SKA_HW;
    const int wavebase = t & ~63;
#pragma unroll
    for (int rep = 0; rep < 10; ++rep) {
        int idx = rep * 256 + t;
        int ch  = idx / 320;             // 320 chunks per channel (10 rows x 32)
        int rem = idx - ch * 320;
        int r   = rem >> 5;
        int c4  = rem & 31;
        int xrow = h0 - 1 + r;
        xrow = xrow < 0 ? 0 : (xrow > 127 ? 127 : xrow);   // clamp (see above)
        const float* gsrc = xb + (size_t)ch * 8 * SKA_HW + (size_t)xrow * SKA_W + c4 * 4;
        __builtin_amdgcn_global_load_lds(
            (const __attribute__((address_space(1))) uint32_t*)gsrc,
            (__attribute__((address_space(3))) uint32_t*)&lds[(size_t)(rep * 256 + wavebase) * 4],
            16, 0, 0);
    }

    // ---- weights: 9 float4/thread, loaded once, reused across all 8 groups
    const float* wbase = wgt + ((size_t)(b * 8 + cw) * 9) * SKA_HW + (size_t)h * SKA_W + w0;
    vf4 wv[9];
#pragma unroll
    for (int k = 0; k < 9; ++k)
        wv[k] = *(const vf4*)(wbase + (size_t)k * SKA_HW);
    // zero boundary taps: row h==0 has no i=0 tap, h==127 no i=2 tap
    if (h == 0)   { wv[0] = (vf4)(0.f); wv[1] = (vf4)(0.f); wv[2] = (vf4)(0.f); }
    if (h == 127) { wv[6] = (vf4)(0.f); wv[7] = (vf4)(0.f); wv[8] = (vf4)(0.f); }

    __syncthreads();   // drains vmcnt (global_load_lds) before LDS reads

    // ---- compute: per group, 3 row taps from LDS; horizontal halos via shuffle
    const size_t obase = (size_t)(b * 64 + cw) * SKA_HW + (size_t)h * SKA_W + w0;
#pragma unroll
    for (int g = 0; g < 8; ++g) {
        vf4 acc = (vf4)(0.f);
#pragma unroll
        for (int i = 0; i < 3; ++i) {
            const float* lrow = &lds[(g * STAGE_ROWS + hl + i) * SKA_W + w0];
            vf4 mid = *(const vf4*)lrow;
            // halos from lane-adjacent chunk (w4 +- 1); lanes 0/32 have w4==0,
            // lanes 31/63 have w4==31, so cross-row shuffles are always masked.
            float xl  = __shfl_up(mid.w, 1);
            xl  = (w4 == 0)  ? 0.f : xl;
            float xr4 = __shfl_down(mid.x, 1);
            xr4 = (w4 == 31) ? 0.f : xr4;
            vf4 wl = wv[i * 3 + 0];
            vf4 wm = wv[i * 3 + 1];
            vf4 wr = wv[i * 3 + 2];
            acc.x += wl.x * xl    + wm.x * mid.x + wr.x * mid.y;
            acc.y += wl.y * mid.x + wm.y * mid.y + wr.y * mid.z;
            acc.z += wl.z * mid.y + wm.z * mid.z + wr.z * mid.w;
            acc.w += wl.w * mid.z + wm.w * mid.w + wr.w * xr4;
        }
        *(vf4*)(out + obase + (size_t)g * 8 * SKA_HW) = acc;
    }
}

extern "C" void kernel_launch(void* const* d_in, const int* in_sizes, int n_in,
                              void* d_out, int out_size, void* d_ws, size_t ws_size,
                              hipStream_t stream) {
    const float* x   = (const float*)d_in[0];  // (8, 64, 128, 128)
    const float* wgt = (const float*)d_in[1];  // (8, 8, 9, 128, 128)
    float* out = (float*)d_out;                // (8, 64, 128, 128)

    // blocks = B * C_w * (H / TILE_ROWS) = 8*8*16 = 1024, 256 threads each
    SKA_44830868635847_kernel<<<1024, 256, 0, stream>>>(x, wgt, out);
}